// Round 2
// baseline (220.321 us; speedup 1.0000x reference)
//
#include <hip/hip_runtime.h>
#include <math.h>

#define IR_LEN  2000
#define PFRAME  80
#define NFRAMES 300
#define NBATCH  2
#define NROWS   (NBATCH*NFRAMES)     // 600
#define T_TOTAL (NFRAMES*PFRAME)     // 24000
#define NCOEF   25
#define NHALF   2049                 // half spectrum f = 0..2048
#define TWO_PI  6.283185307179586f

// ---------------------------------------------------------------------------
// A0: E[row][f] = exp(C[row][f]),  C[f] = sum_k c[k] e^{-2pi i f k/4096}
// One thread per (row, f). Pure VALU, fully parallel (1.23M elements).
// ---------------------------------------------------------------------------
__global__ __launch_bounds__(256) void exp_spec_kernel(
        const float* __restrict__ mc, float2* __restrict__ E) {
    const int idx = blockIdx.x * 256 + threadIdx.x;
    if (idx >= NROWS * NHALF) return;
    const int row = idx / NHALF;
    const int f   = idx - row * NHALF;
    const float* c = mc + row * NCOEF;

    const float ang = -(TWO_PI / 4096.0f) * (float)f;
    float ws, wc; sincosf(ang, &ws, &wc);      // e^{-2pi i f/4096}
    float cr = 1.0f, ci = 0.0f, Cr = 0.0f, Ci = 0.0f;
    #pragma unroll
    for (int k = 0; k < NCOEF; k++) {
        const float cc = c[k];
        Cr += cc * cr; Ci += cc * ci;
        const float nr = cr * wc - ci * ws;
        const float ni = cr * ws + ci * wc;
        cr = nr; ci = ni;
    }
    const float m = expf(Cr);
    float si, co; sincosf(Ci, &si, &co);
    E[idx] = make_float2(m * co, m * si);
}

// ---------------------------------------------------------------------------
// A12: 4096-pt IFFT (real part, first 2000) factored 64x64, split 4 ways by d.
//   f = 64a + b, n = 64c + d
//   G[d][b]  = sum_a E[64a+b] e^{+2pi i a d/64}      (conj-fold for f>2048)
//   G'[d][b] = G[d][b] e^{+2pi i b d/4096}
//   h[64c+d] = (1/4096) Re( sum_b G'[d][b] e^{+2pi i b c/64} )
// Block = (row, quarter q): d in [16q, 16q+16). All twiddles via in-register
// rotation recurrences (no LDS twiddle reads).
// ---------------------------------------------------------------------------
__global__ __launch_bounds__(256) void ifft_kernel(
        const float2* __restrict__ E, float* __restrict__ h_out) {
    __shared__ float EHr[NHALF], EHi[NHALF];     // 16.4 KB
    __shared__ float Gr[16 * 65], Gi[16 * 65];   // 8.3 KB, stride 65

    const int row = blockIdx.x >> 2;
    const int q   = blockIdx.x & 3;
    const int t   = threadIdx.x;

    const float2* Erow = E + row * NHALF;
    for (int i = t; i < NHALF; i += 256) {
        const float2 e = Erow[i];
        EHr[i] = e.x; EHi[i] = e.y;
    }
    __syncthreads();

    // ---- Stage 1: thread owns b = t&63 and 4 consecutive d values ----
    {
        const int b  = t & 63;
        const int dg = t >> 6;                 // 0..3
        const int d0 = q * 16 + dg * 4;        // global d of j=0
        float ar[4] = {0, 0, 0, 0}, ai[4] = {0, 0, 0, 0};
        float rr[4], ri[4], wr[4], wi[4];
        #pragma unroll
        for (int j = 0; j < 4; j++) {
            float s, c; sincosf((TWO_PI / 64.0f) * (float)(d0 + j), &s, &c);
            wr[j] = c; wi[j] = s; rr[j] = 1.0f; ri[j] = 0.0f;
        }
        // a = 0..31: direct read E[64a+b]
        for (int a = 0; a < 32; a++) {
            const float er = EHr[a * 64 + b];
            const float ei = EHi[a * 64 + b];
            #pragma unroll
            for (int j = 0; j < 4; j++) {
                ar[j] += er * rr[j] - ei * ri[j];
                ai[j] += er * ri[j] + ei * rr[j];
                const float nr = rr[j] * wr[j] - ri[j] * wi[j];
                const float ni = rr[j] * wi[j] + ri[j] * wr[j];
                rr[j] = nr; ri[j] = ni;
            }
        }
        // a = 32..63: conjugate fold  E[64a+b] = conj(E[64*(64-a) - b])
        for (int a = 32; a < 64; a++) {
            const int ap = 64 - a;             // 32..1
            const float er =  EHr[ap * 64 - b];
            const float ei = -EHi[ap * 64 - b];
            #pragma unroll
            for (int j = 0; j < 4; j++) {
                ar[j] += er * rr[j] - ei * ri[j];
                ai[j] += er * ri[j] + ei * rr[j];
                const float nr = rr[j] * wr[j] - ri[j] * wi[j];
                const float ni = rr[j] * wi[j] + ri[j] * wr[j];
                rr[j] = nr; ri[j] = ni;
            }
        }
        // twiddle correction e^{2pi i b d/4096} and store G'
        #pragma unroll
        for (int j = 0; j < 4; j++) {
            const int d = d0 + j;
            float s, c; sincosf((TWO_PI / 4096.0f) * (float)(b * d), &s, &c);
            const int dl = dg * 4 + j;
            Gr[dl * 65 + b] = ar[j] * c - ai[j] * s;
            Gi[dl * 65 + b] = ar[j] * s + ai[j] * c;
        }
    }
    __syncthreads();

    // ---- Stage 2: thread owns (d_local = t&15) and c in {t>>4, (t>>4)+16} ----
    {
        const int dl = t & 15;
        const int c0 = t >> 4;                 // 0..15 ; second output c0+16
        const int d  = q * 16 + dl;
        float s0, cc0; sincosf((TWO_PI / 64.0f) * (float)c0, &s0, &cc0);
        const float w1r = cc0, w1i = s0;       // e^{2pi i c0/64}
        const float w2r = -s0, w2i = cc0;      // e^{2pi i (c0+16)/64} = i * w1
        float r1r = 1.0f, r1i = 0.0f, r2r = 1.0f, r2i = 0.0f;
        float acc1 = 0.0f, acc2 = 0.0f;
        for (int b = 0; b < 64; b++) {
            const float gr = Gr[dl * 65 + b];
            const float gi = Gi[dl * 65 + b];
            acc1 += gr * r1r - gi * r1i;
            acc2 += gr * r2r - gi * r2i;
            const float n1r = r1r * w1r - r1i * w1i;
            const float n1i = r1r * w1i + r1i * w1r;
            r1r = n1r; r1i = n1i;
            const float n2r = r2r * w2r - r2i * w2i;
            const float n2i = r2r * w2i + r2i * w2r;
            r2r = n2r; r2i = n2i;
        }
        const int n1 = 64 * c0 + d;            // <= 1023, always valid
        h_out[row * IR_LEN + n1] = acc1 * (1.0f / 4096.0f);
        const int n2 = 64 * (c0 + 16) + d;     // up to 2047
        if (n2 < IR_LEN) h_out[row * IR_LEN + n2] = acc2 * (1.0f / 4096.0f);
    }
}

// ---------------------------------------------------------------------------
// B: time-varying FIR. Block per (batch, frame). Thread = (og = t%20, kc = t/20):
// 4 consecutive outputs o=4*og.., k-chunk kc of 12. Sliding float4 x-window +
// float4 h reads: 3 b128 LDS per 32 FMA (VALU-bound).
// ---------------------------------------------------------------------------
__global__ __launch_bounds__(256) void fir_kernel(
        const float* __restrict__ x, const float* __restrict__ h,
        float* __restrict__ y) {
    __shared__ float h0[IR_LEN], h1[IR_LEN];   // 16 KB
    __shared__ float xw[2080];                 // 8.3 KB
    __shared__ float red0[PFRAME], red1[PFRAME];

    const int row   = blockIdx.x;              // 0..599
    const int batch = row / NFRAMES;
    const int frame = row - batch * NFRAMES;
    const int t0    = frame * PFRAME;
    const int t     = threadIdx.x;
    const int row1  = (frame + 1 < NFRAMES) ? row + 1 : row;

    const float4* hp0 = (const float4*)(h + (size_t)row  * IR_LEN);
    const float4* hp1 = (const float4*)(h + (size_t)row1 * IR_LEN);
    for (int i = t; i < IR_LEN / 4; i += 256) {
        ((float4*)h0)[i] = hp0[i];
        ((float4*)h1)[i] = hp1[i];
    }
    const float* xb = x + batch * T_TOTAL;
    for (int j = t; j < 2080; j += 256) {
        const int xi = t0 - 1999 + j;
        xw[j] = (xi >= 0 && xi < T_TOTAL) ? xb[xi] : 0.0f;
    }
    if (t < PFRAME) { red0[t] = 0.0f; red1[t] = 0.0f; }
    __syncthreads();

    const int og = t % 20;                     // output group: o = 4*og
    const int kc = t / 20;                     // 0..12 (12 => idle)
    if (kc < 12) {
        const int o  = og * 4;
        const int kb = kc * 168;
        const int ke = (kc == 11) ? IR_LEN : kb + 168;
        float s0[4] = {0, 0, 0, 0}, s1[4] = {0, 0, 0, 0};
        int A = 1996 + o - kb;                 // 16B-aligned (o%4==0, kb%4==0)
        float4 hi4 = *(const float4*)&xw[A + 4];
        for (int K = kb; K < ke; K += 4) {
            const float4 lo = *(const float4*)&xw[A];
            const float4 ha = *(const float4*)&h0[K];
            const float4 hb = *(const float4*)&h1[K];
            // x value at (dk, j) = xw[A + 3 + j - dk]
            // dk=0 (h .x): j: lo.w hi4.x hi4.y hi4.z
            s0[0] += ha.x * lo.w;  s0[1] += ha.x * hi4.x; s0[2] += ha.x * hi4.y; s0[3] += ha.x * hi4.z;
            s1[0] += hb.x * lo.w;  s1[1] += hb.x * hi4.x; s1[2] += hb.x * hi4.y; s1[3] += hb.x * hi4.z;
            // dk=1 (h .y): lo.z lo.w hi4.x hi4.y
            s0[0] += ha.y * lo.z;  s0[1] += ha.y * lo.w;  s0[2] += ha.y * hi4.x; s0[3] += ha.y * hi4.y;
            s1[0] += hb.y * lo.z;  s1[1] += hb.y * lo.w;  s1[2] += hb.y * hi4.x; s1[3] += hb.y * hi4.y;
            // dk=2 (h .z): lo.y lo.z lo.w hi4.x
            s0[0] += ha.z * lo.y;  s0[1] += ha.z * lo.z;  s0[2] += ha.z * lo.w;  s0[3] += ha.z * hi4.x;
            s1[0] += hb.z * lo.y;  s1[1] += hb.z * lo.z;  s1[2] += hb.z * lo.w;  s1[3] += hb.z * hi4.x;
            // dk=3 (h .w): lo.x lo.y lo.z lo.w
            s0[0] += ha.w * lo.x;  s0[1] += ha.w * lo.y;  s0[2] += ha.w * lo.z;  s0[3] += ha.w * lo.w;
            s1[0] += hb.w * lo.x;  s1[1] += hb.w * lo.y;  s1[2] += hb.w * lo.z;  s1[3] += hb.w * lo.w;
            hi4 = lo;
            A -= 4;
        }
        #pragma unroll
        for (int j = 0; j < 4; j++) {
            atomicAdd(&red0[o + j], s0[j]);
            atomicAdd(&red1[o + j], s1[j]);
        }
    }
    __syncthreads();
    if (t < PFRAME) {
        const float w = (float)t * (1.0f / (float)PFRAME);
        y[batch * T_TOTAL + t0 + t] = (1.0f - w) * red0[t] + w * red1[t];
    }
}

extern "C" void kernel_launch(void* const* d_in, const int* in_sizes, int n_in,
                              void* d_out, int out_size, void* d_ws, size_t ws_size,
                              hipStream_t stream) {
    const float* x  = (const float*)d_in[0];   // (2, 24000)
    const float* mc = (const float*)d_in[1];   // (2, 300, 25)
    float* y = (float*)d_out;                  // (2, 24000)

    float2* E    = (float2*)d_ws;                                  // 9.84 MB
    float*  h_ws = (float*)((char*)d_ws + (size_t)NROWS * NHALF * sizeof(float2)); // 4.8 MB

    const int nE = NROWS * NHALF;
    exp_spec_kernel<<<(nE + 255) / 256, 256, 0, stream>>>(mc, E);
    ifft_kernel<<<NROWS * 4, 256, 0, stream>>>(E, h_ws);
    fir_kernel<<<NROWS, 256, 0, stream>>>(x, h_ws, y);
}

// Round 3
// 124.614 us; speedup vs baseline: 1.7680x; 1.7680x over previous
//
#include <hip/hip_runtime.h>
#include <math.h>

#define IR_LEN  2000
#define PFRAME  80
#define NFRAMES 300
#define NBATCH  2
#define NROWS   (NBATCH*NFRAMES)     // 600
#define T_TOTAL (NFRAMES*PFRAME)     // 24000
#define NCOEF   25
#define NHALF   2049                 // half spectrum f = 0..2048
#define TWO_PI  6.283185307179586f
#define GS      68                   // G row stride in floats (16B-aligned rows)

// ---------------------------------------------------------------------------
// A0: E[row][f] = exp(C[row][f]),  C[f] = sum_k c[k] e^{-2pi i f k/4096}
// ---------------------------------------------------------------------------
__global__ __launch_bounds__(256) void exp_spec_kernel(
        const float* __restrict__ mc, float2* __restrict__ E) {
    const int idx = blockIdx.x * 256 + threadIdx.x;
    if (idx >= NROWS * NHALF) return;
    const int row = idx / NHALF;
    const int f   = idx - row * NHALF;
    const float* c = mc + row * NCOEF;

    const float ang = -(TWO_PI / 4096.0f) * (float)f;
    float ws, wc; sincosf(ang, &ws, &wc);      // e^{-2pi i f/4096}
    float cr = 1.0f, ci = 0.0f, Cr = 0.0f, Ci = 0.0f;
    #pragma unroll
    for (int k = 0; k < NCOEF; k++) {
        const float cc = c[k];
        Cr += cc * cr; Ci += cc * ci;
        const float nr = cr * wc - ci * ws;
        const float ni = cr * ws + ci * wc;
        cr = nr; ci = ni;
    }
    const float m = expf(Cr);
    float si, co; sincosf(Ci, &si, &co);
    E[idx] = make_float2(m * co, m * si);
}

// ---------------------------------------------------------------------------
// A1: 4096-pt IFFT (real part, first 2000) factored 64x64. One block per row.
//   f = 64a + b, n = 64c + d
//   G[b][d]  = sum_a E[64a+b] e^{+2pi i a d/64}     (conj fold for f > 2048)
//   G'[b][d] = G[b][d] e^{+2pi i b d/4096}
//   h[64c+d] = (1/4096) Re( sum_b G'[b][d] e^{+2pi i b c/64} )
// Stage 1: thread = (dg=t>>4 -> 4 d's, bg=t&15 -> 4 b's); 64 acc FMA + 16
// rotation FMA per a-step, 2x b128 E reads (direct half) / scalar (folded).
// Stage 2: thread = (2 d's = 2*(t&31), cg=t>>5); c in {cg,cg+8,cg+16,cg+24}
// via one rotation chain x constant 8th-root factors (unroll-8, folded).
// ---------------------------------------------------------------------------
__global__ __launch_bounds__(256) void ifft_kernel(
        const float2* __restrict__ E, float* __restrict__ h_out) {
    __shared__ __align__(16) float EHr[2052], EHi[2052];   // 16.4 KB
    __shared__ __align__(16) float Gr[64 * GS], Gi[64 * GS]; // 34.8 KB

    const int row = blockIdx.x;
    const int t   = threadIdx.x;

    const float2* Erow = E + row * NHALF;
    for (int i = t; i < NHALF; i += 256) {
        const float2 e = Erow[i];
        EHr[i] = e.x; EHi[i] = e.y;
    }
    __syncthreads();

    // ---------------- Stage 1 ----------------
    {
        const int b0 = (t & 15) * 4;
        const int d0 = (t >> 4) * 4;
        float ar[4][4] = {{0}}, ai[4][4] = {{0}};
        float rr[4], ri[4], wr[4], wi[4];
        #pragma unroll
        for (int j = 0; j < 4; j++) {
            float s, c; sincosf((TWO_PI / 64.0f) * (float)(d0 + j), &s, &c);
            wr[j] = c; wi[j] = s; rr[j] = 1.0f; ri[j] = 0.0f;
        }
        // direct half: f = 64a + b <= 2047
        for (int a = 0; a < 32; a++) {
            const float4 vr = *(const float4*)&EHr[a * 64 + b0];
            const float4 vi = *(const float4*)&EHi[a * 64 + b0];
            const float er[4] = {vr.x, vr.y, vr.z, vr.w};
            const float ei[4] = {vi.x, vi.y, vi.z, vi.w};
            #pragma unroll
            for (int j = 0; j < 4; j++) {
                #pragma unroll
                for (int i = 0; i < 4; i++) {
                    ar[j][i] += er[i] * rr[j] - ei[i] * ri[j];
                    ai[j][i] += er[i] * ri[j] + ei[i] * rr[j];
                }
                const float nr = rr[j] * wr[j] - ri[j] * wi[j];
                const float ni = rr[j] * wi[j] + ri[j] * wr[j];
                rr[j] = nr; ri[j] = ni;
            }
        }
        // folded half: E[64a+b] = conj(E[4096-64a-b]), source idx descending
        for (int a = 32; a < 64; a++) {
            const int fb = (64 - a) * 64 - b0;     // in [1, 2048]
            const float er[4] = { EHr[fb],  EHr[fb-1],  EHr[fb-2],  EHr[fb-3]};
            const float ei[4] = {-EHi[fb], -EHi[fb-1], -EHi[fb-2], -EHi[fb-3]};
            #pragma unroll
            for (int j = 0; j < 4; j++) {
                #pragma unroll
                for (int i = 0; i < 4; i++) {
                    ar[j][i] += er[i] * rr[j] - ei[i] * ri[j];
                    ai[j][i] += er[i] * ri[j] + ei[i] * rr[j];
                }
                const float nr = rr[j] * wr[j] - ri[j] * wi[j];
                const float ni = rr[j] * wi[j] + ri[j] * wr[j];
                rr[j] = nr; ri[j] = ni;
            }
        }
        // twiddle-correct and write G[b][d] (float4 rows)
        #pragma unroll
        for (int i = 0; i < 4; i++) {
            const int b = b0 + i;
            float orv[4], oiv[4];
            #pragma unroll
            for (int j = 0; j < 4; j++) {
                float s, c;
                sincosf((TWO_PI / 4096.0f) * (float)(b * (d0 + j)), &s, &c);
                orv[j] = ar[j][i] * c - ai[j][i] * s;
                oiv[j] = ar[j][i] * s + ai[j][i] * c;
            }
            *(float4*)&Gr[b * GS + d0] = make_float4(orv[0], orv[1], orv[2], orv[3]);
            *(float4*)&Gi[b * GS + d0] = make_float4(oiv[0], oiv[1], oiv[2], oiv[3]);
        }
    }
    __syncthreads();

    // ---------------- Stage 2 ----------------
    {
        const int dl = (t & 31) * 2;
        const int cg = t >> 5;                     // 0..7
        float swi_, swr_; sincosf((TWO_PI / 64.0f) * (float)cg, &swi_, &swr_);
        const float swr = swr_, swi = swi_;        // step e^{2pi i cg/64}
        float rr = 1.0f, ri = 0.0f;
        float acc00 = 0, acc01 = 0, acc10 = 0, acc11 = 0;
        float acc20 = 0, acc21 = 0, acc30 = 0, acc31 = 0;
        int bb = 0;

#define S2C 0.70710678118654752f
#define STEP2(f8r, f8i, f16r, f16i, f24r, f24i)                                \
        {                                                                      \
            const float2 g_r = *(const float2*)&Gr[bb * GS + dl];              \
            const float2 g_i = *(const float2*)&Gi[bb * GS + dl];              \
            acc00 += g_r.x * rr - g_i.x * ri;                                  \
            acc01 += g_r.y * rr - g_i.y * ri;                                  \
            { const float tr = rr*(f8r) - ri*(f8i), ti = rr*(f8i) + ri*(f8r);  \
              acc10 += g_r.x * tr - g_i.x * ti;                                \
              acc11 += g_r.y * tr - g_i.y * ti; }                              \
            { const float tr = rr*(f16r) - ri*(f16i), ti = rr*(f16i) + ri*(f16r); \
              acc20 += g_r.x * tr - g_i.x * ti;                                \
              acc21 += g_r.y * tr - g_i.y * ti; }                              \
            { const float tr = rr*(f24r) - ri*(f24i), ti = rr*(f24i) + ri*(f24r); \
              acc30 += g_r.x * tr - g_i.x * ti;                                \
              acc31 += g_r.y * tr - g_i.y * ti; }                              \
            { const float nr = rr * swr - ri * swi;                            \
              const float ni = rr * swi + ri * swr;                            \
              rr = nr; ri = ni; }                                              \
            bb++;                                                              \
        }

        for (int grp = 0; grp < 8; grp++) {
            STEP2( 1.0f, 0.0f,   1.0f, 0.0f,   1.0f, 0.0f)
            STEP2( S2C,  S2C,    0.0f, 1.0f,  -S2C,  S2C)
            STEP2( 0.0f, 1.0f,  -1.0f, 0.0f,   0.0f,-1.0f)
            STEP2(-S2C,  S2C,    0.0f,-1.0f,   S2C,  S2C)
            STEP2(-1.0f, 0.0f,   1.0f, 0.0f,  -1.0f, 0.0f)
            STEP2(-S2C, -S2C,    0.0f, 1.0f,   S2C, -S2C)
            STEP2( 0.0f,-1.0f,  -1.0f, 0.0f,   0.0f, 1.0f)
            STEP2( S2C, -S2C,    0.0f,-1.0f,  -S2C, -S2C)
        }
#undef STEP2

        const float sc = 1.0f / 4096.0f;
        float* ho = h_out + row * IR_LEN;
        const float av[4][2] = {{acc00, acc01}, {acc10, acc11},
                                {acc20, acc21}, {acc30, acc31}};
        #pragma unroll
        for (int v = 0; v < 4; v++) {
            const int c = cg + 8 * v;
            #pragma unroll
            for (int e = 0; e < 2; e++) {
                const int n = 64 * c + dl + e;
                if (n < IR_LEN) ho[n] = av[v][e] * sc;
            }
        }
    }
}

// ---------------------------------------------------------------------------
// B: time-varying FIR. Block per (batch, frame). Thread = (og = t%10 -> 8
// outputs, kc = t/10 -> 80-tap chunk). Sliding 12-float x window: per 4-tap
// step 3x b128 LDS for 64 FMA. Partials to LDS slabs, tree-free reduction.
// ---------------------------------------------------------------------------
__global__ __launch_bounds__(256) void fir_kernel(
        const float* __restrict__ x, const float* __restrict__ h,
        float* __restrict__ y) {
    __shared__ __align__(16) float h0[IR_LEN], h1[IR_LEN];   // 16 KB
    __shared__ __align__(16) float xw[2080];                 // 8.3 KB
    __shared__ __align__(16) float red0[2000], red1[2000];   // 16 KB (25 x 80)

    const int row   = blockIdx.x;              // 0..599
    const int batch = row / NFRAMES;
    const int frame = row - batch * NFRAMES;
    const int t0    = frame * PFRAME;
    const int t     = threadIdx.x;
    const int row1  = (frame + 1 < NFRAMES) ? row + 1 : row;

    const float4* hp0 = (const float4*)(h + (size_t)row  * IR_LEN);
    const float4* hp1 = (const float4*)(h + (size_t)row1 * IR_LEN);
    for (int i = t; i < IR_LEN / 4; i += 256) {
        ((float4*)h0)[i] = hp0[i];
        ((float4*)h1)[i] = hp1[i];
    }
    const float* xb = x + batch * T_TOTAL;
    for (int j = t; j < 2080; j += 256) {
        const int xi = t0 - 1999 + j;
        xw[j] = (xi >= 0 && xi < T_TOTAL) ? xb[xi] : 0.0f;
    }
    __syncthreads();

    if (t < 250) {
        const int o0 = (t % 10) * 8;           // outputs o0..o0+7
        const int kb = (t / 10) * 80;          // taps kb..kb+79
        float s0[8] = {0,0,0,0,0,0,0,0}, s1[8] = {0,0,0,0,0,0,0,0};
        int B = 1996 + o0 - kb;                // mult of 4
        float4 w1 = ((const float4*)xw)[B / 4 + 1];
        float4 w2 = ((const float4*)xw)[B / 4 + 2];
        for (int s = 0; s < 20; s++) {
            const float4 w0 = ((const float4*)xw)[B / 4];
            const float4 ha = ((const float4*)h0)[kb / 4 + s];
            const float4 hb = ((const float4*)h1)[kb / 4 + s];
            const float wv[12] = {w0.x, w0.y, w0.z, w0.w,
                                  w1.x, w1.y, w1.z, w1.w,
                                  w2.x, w2.y, w2.z, w2.w};
            const float hav[4] = {ha.x, ha.y, ha.z, ha.w};
            const float hbv[4] = {hb.x, hb.y, hb.z, hb.w};
            #pragma unroll
            for (int jo = 0; jo < 8; jo++) {
                #pragma unroll
                for (int jk = 0; jk < 4; jk++) {
                    const float xv = wv[3 + jo - jk];
                    s0[jo] += hav[jk] * xv;
                    s1[jo] += hbv[jk] * xv;
                }
            }
            w2 = w1; w1 = w0; B -= 4;
        }
        const int rb = (t / 10) * 80 + o0;     // mult of 4
        *(float4*)&red0[rb]     = make_float4(s0[0], s0[1], s0[2], s0[3]);
        *(float4*)&red0[rb + 4] = make_float4(s0[4], s0[5], s0[6], s0[7]);
        *(float4*)&red1[rb]     = make_float4(s1[0], s1[1], s1[2], s1[3]);
        *(float4*)&red1[rb + 4] = make_float4(s1[4], s1[5], s1[6], s1[7]);
    }
    __syncthreads();

    if (t < PFRAME) {
        float S0 = 0.0f, S1 = 0.0f;
        #pragma unroll
        for (int kc = 0; kc < 25; kc++) {
            S0 += red0[kc * 80 + t];
            S1 += red1[kc * 80 + t];
        }
        const float w = (float)t * (1.0f / (float)PFRAME);
        y[batch * T_TOTAL + t0 + t] = (1.0f - w) * S0 + w * S1;
    }
}

extern "C" void kernel_launch(void* const* d_in, const int* in_sizes, int n_in,
                              void* d_out, int out_size, void* d_ws, size_t ws_size,
                              hipStream_t stream) {
    const float* x  = (const float*)d_in[0];   // (2, 24000)
    const float* mc = (const float*)d_in[1];   // (2, 300, 25)
    float* y = (float*)d_out;                  // (2, 24000)

    float2* E    = (float2*)d_ws;                                  // 9.84 MB
    float*  h_ws = (float*)((char*)d_ws + (size_t)NROWS * NHALF * sizeof(float2));

    const int nE = NROWS * NHALF;
    exp_spec_kernel<<<(nE + 255) / 256, 256, 0, stream>>>(mc, E);
    ifft_kernel<<<NROWS, 256, 0, stream>>>(E, h_ws);
    fir_kernel<<<NROWS, 256, 0, stream>>>(x, h_ws, y);
}